// Round 10
// baseline (718.090 us; speedup 1.0000x reference)
//
#include <hip/hip_runtime.h>

typedef __attribute__((ext_vector_type(8))) short short8;
typedef __attribute__((ext_vector_type(4))) float floatx4;
typedef __attribute__((ext_vector_type(2))) unsigned int uintx2;
typedef __attribute__((ext_vector_type(4))) unsigned int uintx4;
typedef unsigned short u16;

#define MFMA(a, b, c) __builtin_amdgcn_mfma_f32_16x16x32_bf16((a), (b), (c), 0, 0, 0)

__device__ __forceinline__ u16 f2bf(float f) {
  unsigned int u = __builtin_bit_cast(unsigned int, f);
  u += ((u >> 16) & 1u) + 0x7fffu;
  return (u16)(u >> 16);
}

__device__ __forceinline__ float softplus_f(float v) {
  float a = __builtin_fabsf(v);
  float e = __expf(-a);
  float l = __logf(1.0f + e);
  return __builtin_fmaxf(v, 0.0f) + l;
}

__device__ __forceinline__ unsigned int pack_sp(float lo, float hi) {
  return (unsigned int)f2bf(softplus_f(lo)) | ((unsigned int)f2bf(softplus_f(hi)) << 16);
}

// out[n*K + k] = bf16(in[k*N + n]); in is K x N row-major fp32
__global__ void transpose_cvt(const float* __restrict__ in, u16* __restrict__ out, int K, int N) {
  __shared__ float tile[32][33];
  const int bn = blockIdx.x * 32, bk = blockIdx.y * 32;
  const int tx = threadIdx.x, ty = threadIdx.y;  // 32 x 8
#pragma unroll
  for (int i = 0; i < 32; i += 8)
    tile[ty + i][tx] = in[(size_t)(bk + ty + i) * N + bn + tx];
  __syncthreads();
#pragma unroll
  for (int i = 0; i < 32; i += 8)
    out[(size_t)(bn + ty + i) * K + bk + tx] = f2bf(tile[tx][ty + i]);
}

__device__ __forceinline__ void gld16(const void* g, void* l) {
  __builtin_amdgcn_global_load_lds((const __attribute__((address_space(1))) void*)g,
                                   (__attribute__((address_space(3))) void*)l, 16, 0, 0);
}

template <int LN>
__device__ __forceinline__ void vwait() {
  if constexpr (LN == 0) asm volatile("s_waitcnt vmcnt(0)" ::: "memory");
  else if constexpr (LN == 2) asm volatile("s_waitcnt vmcnt(2)" ::: "memory");
  else if constexpr (LN == 3) asm volatile("s_waitcnt vmcnt(3)" ::: "memory");
  else if constexpr (LN == 4) asm volatile("s_waitcnt vmcnt(4)" ::: "memory");
}

// -------- BM x 256 GEMM (C = act @ wt^T), full register double-buffer --------
// Half = [BM rows act | 256 rows wt][32 k] bf16 as permuted 16B granules:
// perm h(r)=(r>>1)&3; granule (r,g) at slot f = r*4 + (g ^ h(r)) -> conflict-free
// b128 frag reads, 64B-coalesced staging. 4 half-slots rotate. Phase p:
// {stage half p+2 -> vmcnt ladder -> bar -> issue 12 reads for p+1 (drain under
// MFMA) -> 4*MT MFMA from regs only -> bar}. ACTF32: act is fp32, reg-staged
// with inline bf16 convert + ds_write (lgkmcnt(0) before end bar).
template <int K, int EPI, int BM, bool ACTF32>
__global__ __launch_bounds__(512, 2) void gemmk2(const void* __restrict__ actv,
                                                 const u16* __restrict__ wt,
                                                 void* __restrict__ Cout, int N, int nbn) {
  constexpr int JA = BM / 128;       // A stage ops/thread per half
  constexpr int MT = BM / 32;        // m-frags per wave
  constexpr int HALF_A = BM * 32;    // u16 elems
  constexpr int HALF_T = HALF_A + 8192;
  constexpr int H = K / 32;
  constexpr int LV = JA + 2;         // gld16 per stage (bf16 act path)
  __shared__ u16 lds[4 * HALF_T];
  u16* L = lds;
  const int tid = threadIdx.x, lane = tid & 63, wv = tid >> 6;
  const int l15 = lane & 15, g = lane >> 4;
  const int wvm = wv >> 2, wvn = wv & 3;  // 2 x 4 wave grid; wave owns (BM/2)m x 64n
  const int nwg = gridDim.x, o = blockIdx.x;
  const int sw = (o & 7) * (nwg >> 3) + (o >> 3);  // XCD swizzle (nwg % 8 == 0)
  const int bm = sw / nbn, bn = sw % nbn;
  const size_t am0 = (size_t)bm * BM;
  const size_t wn0 = (size_t)bn * 256;

  // loop-invariant fragment offsets (u16 elems within a half)
  int bfo[MT], afo[4];
#pragma unroll
  for (int mt = 0; mt < MT; ++mt) {
    const int r = wvm * (BM / 2) + mt * 16 + l15;
    bfo[mt] = (r * 4 + (g ^ ((r >> 1) & 3))) * 8;
  }
#pragma unroll
  for (int t = 0; t < 4; ++t) {
    const int r = wvn * 64 + t * 16 + l15;
    afo[t] = HALF_A + (r * 4 + (g ^ ((r >> 1) & 3))) * 8;
  }
  // stage bases: granule G = j*512 + tid; r = j*128 + (tid>>2); gg invariant in j
  const int rt = tid >> 2, ggt = (tid & 3) ^ ((rt >> 1) & 3);
  const int dstt = tid * 8;
  const u16* asrcb = nullptr;
  const float* fsrcb = nullptr;
  if constexpr (ACTF32) fsrcb = (const float*)actv + (am0 + rt) * K + ggt * 8;
  else asrcb = (const u16*)actv + (am0 + rt) * K + ggt * 8;
  const u16* wsrcb = wt + (wn0 + rt) * K + ggt * 8;

#define STG_W(hh)                                                                  \
  _Pragma("unroll") for (int j = 0; j < 2; ++j)                                    \
      gld16(wsrcb + (size_t)j * 128 * K + (hh) * 32,                               \
            L + ((hh) & 3) * HALF_T + HALF_A + j * 4096 + dstt);
#define STG_A(hh)                                                                  \
  _Pragma("unroll") for (int j = 0; j < JA; ++j)                                   \
      gld16(asrcb + (size_t)j * 128 * K + (hh) * 32,                               \
            L + ((hh) & 3) * HALF_T + j * 4096 + dstt);
#define STG_F_LOAD(hh, AV)                                                         \
  _Pragma("unroll") for (int j = 0; j < JA; ++j) {                                 \
    AV[j][0] = *(const floatx4*)(fsrcb + (size_t)j * 128 * K + (hh) * 32);         \
    AV[j][1] = *(const floatx4*)(fsrcb + (size_t)j * 128 * K + (hh) * 32 + 4);     \
  }
#define STG_F_WRITE(hh, AV)                                                        \
  _Pragma("unroll") for (int j = 0; j < JA; ++j) {                                 \
    uintx4 w_;                                                                     \
    w_.x = (unsigned)f2bf(AV[j][0].x) | ((unsigned)f2bf(AV[j][0].y) << 16);        \
    w_.y = (unsigned)f2bf(AV[j][0].z) | ((unsigned)f2bf(AV[j][0].w) << 16);        \
    w_.z = (unsigned)f2bf(AV[j][1].x) | ((unsigned)f2bf(AV[j][1].y) << 16);        \
    w_.w = (unsigned)f2bf(AV[j][1].z) | ((unsigned)f2bf(AV[j][1].w) << 16);        \
    *(uintx4*)(L + ((hh) & 3) * HALF_T + j * 4096 + dstt) = w_;                    \
  }

  floatx4 acc[4][MT];
  const floatx4 z4 = {0.f, 0.f, 0.f, 0.f};
#pragma unroll
  for (int t = 0; t < 4; ++t)
#pragma unroll
    for (int mt = 0; mt < MT; ++mt) acc[t][mt] = z4;

  short8 bfA[MT], bfB[MT], afA[4], afB[4];

  // prologue: stage halves 0,1; establish 0; preload CUR regs from slot 0
  if constexpr (ACTF32) {
    floatx4 av[JA][2];
    STG_F_LOAD(0, av) STG_W(0)
    vwait<2>();
    STG_F_WRITE(0, av)
    STG_F_LOAD(1, av) STG_W(1)
    vwait<2>();
    STG_F_WRITE(1, av)
    asm volatile("s_waitcnt lgkmcnt(0)" ::: "memory");
  } else {
    STG_A(0) STG_W(0)
    STG_A(1) STG_W(1)
    vwait<LV>();
  }
  __builtin_amdgcn_s_barrier();
  asm volatile("" ::: "memory");
#pragma unroll
  for (int mt = 0; mt < MT; ++mt) bfA[mt] = *(const short8*)(L + bfo[mt]);
#pragma unroll
  for (int t = 0; t < 4; ++t) afA[t] = *(const short8*)(L + afo[t]);

#define PHASE_BODY(p_, CAF, CBF, NAF, NBF)                                         \
  {                                                                                \
    if ((p_) + 2 < H) {                                                            \
      if constexpr (ACTF32) {                                                      \
        floatx4 av[JA][2];                                                         \
        STG_F_LOAD((p_) + 2, av)                                                   \
        STG_W((p_) + 2)                                                            \
        vwait<2>();                                                                \
        STG_F_WRITE((p_) + 2, av)                                                  \
      } else {                                                                     \
        STG_A((p_) + 2)                                                            \
        STG_W((p_) + 2)                                                            \
        vwait<LV>();                                                               \
      }                                                                            \
    } else {                                                                       \
      vwait<0>();                                                                  \
    }                                                                              \
    __builtin_amdgcn_s_barrier();                                                  \
    asm volatile("" ::: "memory");                                                 \
    if ((p_) + 1 < H) {                                                            \
      const int sn_ = (((p_) + 1) & 3) * HALF_T;                                   \
      _Pragma("unroll") for (int mt = 0; mt < MT; ++mt)                            \
          NBF[mt] = *(const short8*)(L + sn_ + bfo[mt]);                           \
      _Pragma("unroll") for (int t = 0; t < 4; ++t)                                \
          NAF[t] = *(const short8*)(L + sn_ + afo[t]);                             \
    }                                                                              \
    __builtin_amdgcn_s_setprio(1);                                                 \
    _Pragma("unroll") for (int t = 0; t < 4; ++t)                                  \
        _Pragma("unroll") for (int mt = 0; mt < MT; ++mt)                          \
            acc[t][mt] = MFMA(CAF[t], CBF[mt], acc[t][mt]);                        \
    __builtin_amdgcn_s_setprio(0);                                                 \
    if constexpr (ACTF32) asm volatile("s_waitcnt lgkmcnt(0)" ::: "memory");       \
    asm volatile("" ::: "memory");                                                 \
    __builtin_amdgcn_s_barrier();                                                  \
    asm volatile("" ::: "memory");                                                 \
  }

#pragma unroll 1
  for (int it = 0; it < H / 2; ++it) {
    PHASE_BODY(2 * it, afA, bfA, afB, bfB)
    PHASE_BODY(2 * it + 1, afB, bfB, afA, bfA)
  }
#undef PHASE_BODY
#undef STG_W
#undef STG_A
#undef STG_F_LOAD
#undef STG_F_WRITE

  // ---- epilogue: all stages retired (tail vmcnt(0)), LDS reusable ----
  if constexpr (EPI == 0) {
    // softplus -> bf16 C via LDS transpose; one pass (BM=256: 128 KB)
    u16* cl = L;
#pragma unroll
    for (int t = 0; t < 4; ++t)
#pragma unroll
      for (int mt = 0; mt < MT; ++mt) {
        const int m = wvm * (BM / 2) + mt * 16 + l15;
        const int n0 = wvn * 64 + t * 16 + g * 4;
        const int j = n0 >> 3, hh = (n0 >> 2) & 1;
        uintx2 pk;
        pk.x = pack_sp(acc[t][mt].x, acc[t][mt].y);
        pk.y = pack_sp(acc[t][mt].z, acc[t][mt].w);
        *(uintx2*)(cl + m * 256 + ((j ^ (m & 7)) << 3) + (hh << 2)) = pk;
      }
    __syncthreads();
    u16* outp = (u16*)Cout;
#pragma unroll
    for (int i = 0; i < BM / 16; ++i) {
      const int c = i * 512 + tid;
      const int m = c >> 5, j = c & 31;
      uintx4 v = *(const uintx4*)(cl + m * 256 + ((j ^ (m & 7)) << 3));
      *(uintx4*)(outp + (am0 + m) * N + wn0 + j * 8) = v;
    }
  } else {
    // fp32 C in two (BM/2)-row passes
    float* cf = (float*)L;
    constexpr int R = BM / 2;
#pragma unroll
    for (int q = 0; q < 2; ++q) {
      if (q) __syncthreads();
      if (wvm == q) {
#pragma unroll
        for (int t = 0; t < 4; ++t)
#pragma unroll
          for (int mt = 0; mt < MT; ++mt) {
            const int m = mt * 16 + l15;                     // 0..R-1
            const int p = (wvn * 64 + t * 16 + g * 4) >> 1;  // even 2-float slot
            *(floatx4*)(cf + m * 256 + ((p ^ ((m & 7) << 1)) << 1)) = acc[t][mt];
          }
      }
      __syncthreads();
      float* outp = (float*)Cout;
#pragma unroll
      for (int i = 0; i < R / 8; ++i) {
        const int c = i * 512 + tid;
        const int m = c >> 6, cc = c & 63;
        const int p = cc * 2;
        floatx4 v = *(const floatx4*)(cf + m * 256 + ((p ^ ((m & 7) << 1)) << 1));
        *(floatx4*)(outp + (am0 + q * R + m) * N + wn0 + cc * 4) = v;
      }
    }
  }
}

// ---------------- fallback: R1 fused kernel (used only if ws is too small) ----------------
__global__ __launch_bounds__(512, 2) void mlp3_fused(const float* __restrict__ x,
                                                     const u16* __restrict__ w1t,
                                                     const u16* __restrict__ w2t,
                                                     const u16* __restrict__ w3t,
                                                     float* __restrict__ out) {
  __shared__ u16 h1s[64 * 1024];
  __shared__ u16 xs[64 * 256];
  const int tid = threadIdx.x, lane = tid & 63, wv = tid >> 6;
  const int l15 = lane & 15, g = lane >> 4;
  const size_t m0 = (size_t)blockIdx.x * 64;
  const floatx4 z4 = {0.f, 0.f, 0.f, 0.f};
  {
    const float* xp = x + m0 * 256;
#pragma unroll
    for (int r = 0; r < 8; ++r) {
      int idx4 = r * 512 + tid;
      int m = idx4 >> 6, k = (idx4 & 63) << 2;
      floatx4 v = *(const floatx4*)(xp + m * 256 + k);
      uintx2 pk;
      pk.x = (unsigned)f2bf(v.x) | ((unsigned)f2bf(v.y) << 16);
      pk.y = (unsigned)f2bf(v.z) | ((unsigned)f2bf(v.w) << 16);
      *(uintx2*)(xs + ((m * 256 + k) ^ ((m & 7) << 3))) = pk;
    }
  }
  __syncthreads();
#pragma unroll 1
  for (int c = 0; c < 4; ++c) {
    floatx4 acc[2][4];
#pragma unroll
    for (int t = 0; t < 2; ++t)
#pragma unroll
      for (int mt = 0; mt < 4; ++mt) acc[t][mt] = z4;
    const u16* p0 = w1t + (size_t)(c * 256 + wv * 32 + l15) * 256;
#pragma unroll
    for (int ks = 0; ks < 8; ++ks) {
      const int k = ks * 32 + g * 8;
      short8 a0 = *(const short8*)(p0 + k);
      short8 a1 = *(const short8*)(p0 + 16 * 256 + k);
      short8 b0 = *(const short8*)(xs + (((0 * 16 + l15) * 256 + k) ^ ((l15 & 7) << 3)));
      short8 b1 = *(const short8*)(xs + (((1 * 16 + l15) * 256 + k) ^ ((l15 & 7) << 3)));
      short8 b2 = *(const short8*)(xs + (((2 * 16 + l15) * 256 + k) ^ ((l15 & 7) << 3)));
      short8 b3 = *(const short8*)(xs + (((3 * 16 + l15) * 256 + k) ^ ((l15 & 7) << 3)));
      acc[0][0] = MFMA(a0, b0, acc[0][0]); acc[0][1] = MFMA(a0, b1, acc[0][1]);
      acc[0][2] = MFMA(a0, b2, acc[0][2]); acc[0][3] = MFMA(a0, b3, acc[0][3]);
      acc[1][0] = MFMA(a1, b0, acc[1][0]); acc[1][1] = MFMA(a1, b1, acc[1][1]);
      acc[1][2] = MFMA(a1, b2, acc[1][2]); acc[1][3] = MFMA(a1, b3, acc[1][3]);
    }
#pragma unroll
    for (int t = 0; t < 2; ++t)
#pragma unroll
      for (int mt = 0; mt < 4; ++mt) {
        const int n1 = c * 256 + wv * 32 + t * 16 + g * 4;
        const int m = mt * 16 + l15;
        uintx2 pk;
        pk.x = pack_sp(acc[t][mt].x, acc[t][mt].y);
        pk.y = pack_sp(acc[t][mt].z, acc[t][mt].w);
        *(uintx2*)(h1s + ((m * 1024 + n1) ^ ((m & 7) << 3))) = pk;
      }
  }
  __syncthreads();
  floatx4 acc3[2][4];
#pragma unroll
  for (int t = 0; t < 2; ++t)
#pragma unroll
    for (int mt = 0; mt < 4; ++mt) acc3[t][mt] = z4;
#pragma unroll 1
  for (int c2 = 0; c2 < 4; ++c2) {
    floatx4 acc2[2][4];
#pragma unroll
    for (int t = 0; t < 2; ++t)
#pragma unroll
      for (int mt = 0; mt < 4; ++mt) acc2[t][mt] = z4;
    {
      const u16* p0 = w2t + (size_t)(c2 * 256 + wv * 32 + l15) * 1024;
#pragma unroll 4
      for (int ks = 0; ks < 32; ++ks) {
        const int k = ks * 32 + g * 8;
        short8 a0 = *(const short8*)(p0 + k);
        short8 a1 = *(const short8*)(p0 + 16 * 1024 + k);
        short8 b0 = *(const short8*)(h1s + (((0 * 16 + l15) * 1024 + k) ^ ((l15 & 7) << 3)));
        short8 b1 = *(const short8*)(h1s + (((1 * 16 + l15) * 1024 + k) ^ ((l15 & 7) << 3)));
        short8 b2 = *(const short8*)(h1s + (((2 * 16 + l15) * 1024 + k) ^ ((l15 & 7) << 3)));
        short8 b3 = *(const short8*)(h1s + (((3 * 16 + l15) * 1024 + k) ^ ((l15 & 7) << 3)));
        acc2[0][0] = MFMA(a0, b0, acc2[0][0]); acc2[0][1] = MFMA(a0, b1, acc2[0][1]);
        acc2[0][2] = MFMA(a0, b2, acc2[0][2]); acc2[0][3] = MFMA(a0, b3, acc2[0][3]);
        acc2[1][0] = MFMA(a1, b0, acc2[1][0]); acc2[1][1] = MFMA(a1, b1, acc2[1][1]);
        acc2[1][2] = MFMA(a1, b2, acc2[1][2]); acc2[1][3] = MFMA(a1, b3, acc2[1][3]);
      }
    }
    __syncthreads();
#pragma unroll
    for (int t = 0; t < 2; ++t)
#pragma unroll
      for (int mt = 0; mt < 4; ++mt) {
        const int n2l = wv * 32 + t * 16 + g * 4;
        const int m = mt * 16 + l15;
        uintx2 pk;
        pk.x = pack_sp(acc2[t][mt].x, acc2[t][mt].y);
        pk.y = pack_sp(acc2[t][mt].z, acc2[t][mt].w);
        *(uintx2*)(xs + ((m * 256 + n2l) ^ ((m & 7) << 3))) = pk;
      }
    __syncthreads();
    {
      const u16* p0 = w3t + (size_t)(wv * 32 + l15) * 1024 + c2 * 256;
#pragma unroll
      for (int ks = 0; ks < 8; ++ks) {
        const int k = ks * 32 + g * 8;
        short8 a0 = *(const short8*)(p0 + k);
        short8 a1 = *(const short8*)(p0 + 16 * 1024 + k);
        short8 b0 = *(const short8*)(xs + (((0 * 16 + l15) * 256 + k) ^ ((l15 & 7) << 3)));
        short8 b1 = *(const short8*)(xs + (((1 * 16 + l15) * 256 + k) ^ ((l15 & 7) << 3)));
        short8 b2 = *(const short8*)(xs + (((2 * 16 + l15) * 256 + k) ^ ((l15 & 7) << 3)));
        short8 b3 = *(const short8*)(xs + (((3 * 16 + l15) * 256 + k) ^ ((l15 & 7) << 3)));
        acc3[0][0] = MFMA(a0, b0, acc3[0][0]); acc3[0][1] = MFMA(a0, b1, acc3[0][1]);
        acc3[0][2] = MFMA(a0, b2, acc3[0][2]); acc3[0][3] = MFMA(a0, b3, acc3[0][3]);
        acc3[1][0] = MFMA(a1, b0, acc3[1][0]); acc3[1][1] = MFMA(a1, b1, acc3[1][1]);
        acc3[1][2] = MFMA(a1, b2, acc3[1][2]); acc3[1][3] = MFMA(a1, b3, acc3[1][3]);
      }
    }
  }
#pragma unroll
  for (int t = 0; t < 2; ++t)
#pragma unroll
    for (int mt = 0; mt < 4; ++mt) {
      const int n3 = wv * 32 + t * 16 + g * 4;
      const int m = mt * 16 + l15;
      *(floatx4*)(out + (m0 + m) * 256 + n3) = acc3[t][mt];
    }
}

extern "C" void kernel_launch(void* const* d_in, const int* in_sizes, int n_in,
                              void* d_out, int out_size, void* d_ws, size_t ws_size,
                              hipStream_t stream) {
  const float* x = (const float*)d_in[0];
  const float* w1 = (const float*)d_in[1];
  const float* w2 = (const float*)d_in[2];
  const float* w3 = (const float*)d_in[3];
  float* out = (float*)d_out;
  const size_t M = 131072;

  u16* w1t = (u16*)d_ws;                      // [1024][256]
  u16* w2t = w1t + 1024 * 256;                // [1024][1024]
  u16* w3t = w2t + 1024 * 1024;               // [256][1024]
  u16* bufA = w3t + 256 * 1024;               // h1: CM x 1024 bf16
  const size_t weights_el = 1024 * 256 + 1024 * 1024 + 256 * 1024;

  // largest chunk that fits: weights + 2 buffers of CM*1024 bf16.
  // CM=32768 keeps h1+h2 (134 MB) L3-resident.
  size_t CM = 0;
  const size_t cands[4] = {32768, 16384, 8192, 4096};
  for (int i = 0; i < 4; ++i) {
    size_t need = (weights_el + 2 * cands[i] * 1024) * sizeof(u16);
    if (ws_size >= need) { CM = cands[i]; break; }
  }

  dim3 tb(32, 8);
  transpose_cvt<<<dim3(32, 8), tb, 0, stream>>>(w1, w1t, 256, 1024);
  transpose_cvt<<<dim3(32, 32), tb, 0, stream>>>(w2, w2t, 1024, 1024);
  transpose_cvt<<<dim3(8, 32), tb, 0, stream>>>(w3, w3t, 1024, 256);

  if (CM) {
    u16* bufB = bufA + CM * 1024;
    const int nchunk = (int)(M / CM);
    for (int ci = 0; ci < nchunk; ++ci) {
      const float* xc = x + (size_t)ci * CM * 256;
      float* oc = out + (size_t)ci * CM * 256;
      gemmk2<256, 0, 256, true><<<(int)(CM / 256) * 4, 512, 0, stream>>>(xc, w1t, bufA, 1024, 4);
      gemmk2<1024, 0, 256, false><<<(int)(CM / 256) * 4, 512, 0, stream>>>(bufA, w2t, bufB, 1024, 4);
      gemmk2<1024, 1, 128, false><<<(int)(CM / 128), 512, 0, stream>>>(bufB, w3t, oc, 256, 1);
    }
  } else {
    mlp3_fused<<<M / 64, 512, 0, stream>>>(x, w1t, w2t, w3t, out);
  }
}